// Round 3
// baseline (2049.294 us; speedup 1.0000x reference)
//
#include <hip/hip_runtime.h>

#define N_NODES 50000
#define VOCAB   5000
#define KPAD1   5024
#define HID     64
#define HEADS   4
#define NCLS    20
#define NGRAPH  128
#define N_EDGES 1600000
#define ETOT    (N_EDGES + N_NODES)
#define SCAN_BLKS ((N_NODES + 255) / 256)

typedef __attribute__((ext_vector_type(8))) short short8;
typedef __attribute__((ext_vector_type(4))) float f32x4;

__device__ inline ushort f2bf(float x) {
  union { float f; unsigned u; } c; c.f = x;
  unsigned r = (c.u + 0x7fffu + ((c.u >> 16) & 1u)) >> 16;
  return (ushort)r;
}
__device__ inline float bf2f(ushort u) {
  union { unsigned u; float f; } c; c.u = (unsigned)u << 16;
  return c.f;
}

// ---------------- weight convert + transpose via LDS tile: Bt[n][k] = bf16(W[k][n]) ----------------
__global__ __launch_bounds__(256) void cvtT_tile(const float* __restrict__ W,
                                                 ushort* __restrict__ Bt, int K, int KP) {
  __shared__ ushort tile[64][65];
  int t = threadIdx.x;
  int k0 = blockIdx.x * 64;
  int n = t & 63;
  for (int kk = t >> 6; kk < 64; kk += 4) {
    int k = k0 + kk;
    tile[n][kk] = (k < K) ? f2bf(W[(size_t)k * 64 + n]) : (ushort)0;
  }
  __syncthreads();
  int kk = t & 63;
  for (int nn = t >> 6; nn < 64; nn += 4) {
    int k = k0 + kk;
    if (k < KP) Bt[(size_t)nn * KP + k] = tile[nn][kk];
  }
}

// ---------------- GEMM1: h1[M,64](bf16) = x[M,5000](f32) @ W1, fused al dots (H=4) ----------------
__global__ __launch_bounds__(128) void gemm1_kernel(const float* __restrict__ A,
    const ushort* __restrict__ Bt, ushort* __restrict__ Dh,
    float* __restrict__ alS, float* __restrict__ alD,
    const float* __restrict__ a_src, const float* __restrict__ a_dst, int M) {
  int gt = blockIdx.x * 128 + threadIdx.x;
  int gw = gt >> 6, lane = gt & 63;
  int lr = lane & 15, quad = lane >> 4;
  int m0 = gw * 16;
  if (m0 >= M) return;
  const float*  ap = A  + (size_t)(m0 + lr) * VOCAB + quad * 8;
  const ushort* bp = Bt + (size_t)lr * KPAD1 + quad * 8;
  f32x4 acc[4] = {{0,0,0,0},{0,0,0,0},{0,0,0,0},{0,0,0,0}};
  constexpr int KF = (VOCAB / 32) * 32;  // 4992
  #pragma unroll 2
  for (int k0 = 0; k0 < KF; k0 += 32) {
    f32x4 v0 = __builtin_nontemporal_load((const f32x4*)(ap + k0));
    f32x4 v1 = __builtin_nontemporal_load((const f32x4*)(ap + k0 + 4));
    short8 b0 = *(const short8*)(bp + k0);
    short8 b1 = *(const short8*)(bp + 16 * KPAD1 + k0);
    short8 b2 = *(const short8*)(bp + 32 * KPAD1 + k0);
    short8 b3 = *(const short8*)(bp + 48 * KPAD1 + k0);
    short8 af;
    #pragma unroll
    for (int j = 0; j < 4; ++j) { af[j] = (short)f2bf(v0[j]); af[4 + j] = (short)f2bf(v1[j]); }
    acc[0] = __builtin_amdgcn_mfma_f32_16x16x32_bf16(af, b0, acc[0], 0, 0, 0);
    acc[1] = __builtin_amdgcn_mfma_f32_16x16x32_bf16(af, b1, acc[1], 0, 0, 0);
    acc[2] = __builtin_amdgcn_mfma_f32_16x16x32_bf16(af, b2, acc[2], 0, 0, 0);
    acc[3] = __builtin_amdgcn_mfma_f32_16x16x32_bf16(af, b3, acc[3], 0, 0, 0);
  }
  {  // K tail (5000-4992=8): only quad 0 has valid A cols; Bt is zero-padded
    int k0 = KF;
    f32x4 v0 = {0,0,0,0}, v1 = {0,0,0,0};
    if (quad == 0) {
      v0 = *(const f32x4*)(ap + k0);
      v1 = *(const f32x4*)(ap + k0 + 4);
    }
    short8 b0 = *(const short8*)(bp + k0);
    short8 b1 = *(const short8*)(bp + 16 * KPAD1 + k0);
    short8 b2 = *(const short8*)(bp + 32 * KPAD1 + k0);
    short8 b3 = *(const short8*)(bp + 48 * KPAD1 + k0);
    short8 af;
    #pragma unroll
    for (int j = 0; j < 4; ++j) { af[j] = (short)f2bf(v0[j]); af[4 + j] = (short)f2bf(v1[j]); }
    acc[0] = __builtin_amdgcn_mfma_f32_16x16x32_bf16(af, b0, acc[0], 0, 0, 0);
    acc[1] = __builtin_amdgcn_mfma_f32_16x16x32_bf16(af, b1, acc[1], 0, 0, 0);
    acc[2] = __builtin_amdgcn_mfma_f32_16x16x32_bf16(af, b2, acc[2], 0, 0, 0);
    acc[3] = __builtin_amdgcn_mfma_f32_16x16x32_bf16(af, b3, acc[3], 0, 0, 0);
  }
  // C/D: col = ct*16+lr, row = m0 + quad*4 + r
  float a0 = a_src[lane], d0 = a_dst[lane];  // a_src[h*16+c] at lane h*16+c
  #pragma unroll
  for (int ct = 0; ct < 4; ++ct) {
    float av = __shfl(a0, ct * 16 + lr);
    float dv = __shfl(d0, ct * 16 + lr);
    #pragma unroll
    for (int r = 0; r < 4; ++r) {
      int grow = m0 + quad * 4 + r;
      Dh[(size_t)grow * 64 + ct * 16 + lr] = f2bf(acc[ct][r]);
      float s = acc[ct][r] * av;
      float d = acc[ct][r] * dv;
      s += __shfl_xor(s, 1); d += __shfl_xor(d, 1);
      s += __shfl_xor(s, 2); d += __shfl_xor(d, 2);
      s += __shfl_xor(s, 4); d += __shfl_xor(d, 4);
      s += __shfl_xor(s, 8); d += __shfl_xor(d, 8);
      if (lr == r * 4 + ct) {
        alS[(size_t)grow * 4 + ct] = s;
        alD[(size_t)grow * 4 + ct] = d;
      }
    }
  }
}

// ---------------- GEMM2: h2[M,64](bf16) = h1b[M,64](bf16) @ W2, fused al dots (H=1) ----------------
__global__ __launch_bounds__(128) void gemm2_kernel(const ushort* __restrict__ A,
    const ushort* __restrict__ Bt, ushort* __restrict__ Dh,
    float* __restrict__ alS, float* __restrict__ alD,
    const float* __restrict__ a_src, const float* __restrict__ a_dst, int M) {
  int gt = blockIdx.x * 128 + threadIdx.x;
  int gw = gt >> 6, lane = gt & 63;
  int lr = lane & 15, quad = lane >> 4;
  int m0 = gw * 16;
  if (m0 >= M) return;
  const ushort* ap = A  + (size_t)(m0 + lr) * 64 + quad * 8;
  const ushort* bp = Bt + (size_t)lr * 64 + quad * 8;
  f32x4 acc[4] = {{0,0,0,0},{0,0,0,0},{0,0,0,0},{0,0,0,0}};
  #pragma unroll
  for (int k0 = 0; k0 < 64; k0 += 32) {
    short8 af = *(const short8*)(ap + k0);
    #pragma unroll
    for (int ct = 0; ct < 4; ++ct) {
      short8 b = *(const short8*)(bp + ct * 16 * 64 + k0);
      acc[ct] = __builtin_amdgcn_mfma_f32_16x16x32_bf16(af, b, acc[ct], 0, 0, 0);
    }
  }
  float a0 = a_src[lane], d0 = a_dst[lane];
  float av[4], dv[4];
  #pragma unroll
  for (int ct = 0; ct < 4; ++ct) {
    av[ct] = __shfl(a0, ct * 16 + lr);
    dv[ct] = __shfl(d0, ct * 16 + lr);
  }
  #pragma unroll
  for (int r = 0; r < 4; ++r) {
    int grow = m0 + quad * 4 + r;
    float s = 0.f, d = 0.f;
    #pragma unroll
    for (int ct = 0; ct < 4; ++ct) {
      Dh[(size_t)grow * 64 + ct * 16 + lr] = f2bf(acc[ct][r]);
      s += acc[ct][r] * av[ct];
      d += acc[ct][r] * dv[ct];
    }
    s += __shfl_xor(s, 1); d += __shfl_xor(d, 1);
    s += __shfl_xor(s, 2); d += __shfl_xor(d, 2);
    s += __shfl_xor(s, 4); d += __shfl_xor(d, 4);
    s += __shfl_xor(s, 8); d += __shfl_xor(d, 8);
    if (lr == r) { alS[grow] = s; alD[grow] = d; }
  }
}

// ---------------- CSR build ----------------
__global__ void hist_kernel(const int* __restrict__ dstA, int* __restrict__ deg, int E, int Etot) {
  int i = blockIdx.x * blockDim.x + threadIdx.x;
  if (i >= Etot) return;
  int d = (i < E) ? dstA[i] : (i - E);
  atomicAdd(&deg[d], 1);
}

__global__ __launch_bounds__(256) void scan_blk(const int* __restrict__ deg,
    int* __restrict__ excl, int* __restrict__ bsum, int n) {
  __shared__ int ws[4];
  int t = threadIdx.x, lane = t & 63, w = t >> 6;
  int i = blockIdx.x * 256 + t;
  int v = (i < n) ? deg[i] : 0;
  int x = v;
  #pragma unroll
  for (int off = 1; off < 64; off <<= 1) {
    int y = __shfl_up(x, off, 64);
    if (lane >= off) x += y;
  }
  if (lane == 63) ws[w] = x;
  __syncthreads();
  int add = 0;
  for (int k = 0; k < w; ++k) add += ws[k];
  x += add;
  if (i < n) excl[i] = x - v;
  if (t == 255) bsum[blockIdx.x] = x;
}

__global__ __launch_bounds__(256) void scan_top(const int* __restrict__ bsum,
    int* __restrict__ boff, int* __restrict__ indptr, int nb, int n) {
  __shared__ int ws[4];
  int t = threadIdx.x, lane = t & 63, w = t >> 6;
  int v = (t < nb) ? bsum[t] : 0;
  int x = v;
  #pragma unroll
  for (int off = 1; off < 64; off <<= 1) {
    int y = __shfl_up(x, off, 64);
    if (lane >= off) x += y;
  }
  if (lane == 63) ws[w] = x;
  __syncthreads();
  int add = 0;
  for (int k = 0; k < w; ++k) add += ws[k];
  x += add;
  boff[t] = x - v;
  if (t == nb - 1) indptr[n] = x;
}

__global__ void scan_add(int* __restrict__ indptr, const int* __restrict__ boff, int n) {
  int i = blockIdx.x * blockDim.x + threadIdx.x;
  if (i < n) indptr[i] += boff[i >> 8];
}

__global__ void scatter_kernel(const int* __restrict__ srcA, const int* __restrict__ dstA,
                               const int* __restrict__ indptr, int* __restrict__ fill,
                               int* __restrict__ srcs, int E, int Etot) {
  int i = blockIdx.x * blockDim.x + threadIdx.x;
  if (i >= Etot) return;
  int d, s;
  if (i < E) { d = dstA[i]; s = srcA[i]; } else { d = i - E; s = d; }
  int pos = indptr[d] + atomicAdd(&fill[d], 1);
  srcs[pos] = s;
}

// ---------------- per-dst online-softmax aggregation (bf16 gathers) + bias + ELU ----------------
template<int H, typename OT>
__global__ __launch_bounds__(256) void agg_kernel(const ushort* __restrict__ h,
    const float* __restrict__ alS, const float* __restrict__ alD,
    const int* __restrict__ indptr, const int* __restrict__ srcs,
    const float* __restrict__ bias, OT* __restrict__ out, int n) {
  int wid = (blockIdx.x * blockDim.x + threadIdx.x) >> 6;
  int lane = threadIdx.x & 63;
  if (wid >= n) return;
  constexpr int C = 64 / H;
  int head = lane / C;
  float ald = alD[wid * H + head];
  int j0 = indptr[wid], j1 = indptr[wid + 1];
  float m = -3.0e38f, ssum = 0.f, acc = 0.f;
  int p0 = srcs[j0], p1 = srcs[j0 + 1], p2 = srcs[j0 + 2], p3 = srcs[j0 + 3];
  for (int j = j0; j < j1; j += 4) {
    int rem = j1 - j;
    int s0 = p0;
    int s1 = (rem > 1) ? p1 : p0;
    int s2 = (rem > 2) ? p2 : p0;
    int s3 = (rem > 3) ? p3 : p0;
    int jn = j + 4;
    if (jn < j1) { p0 = srcs[jn]; p1 = srcs[jn + 1]; p2 = srcs[jn + 2]; p3 = srcs[jn + 3]; }
    float e0 = alS[s0 * H + head] + ald;
    float e1 = alS[s1 * H + head] + ald;
    float e2 = alS[s2 * H + head] + ald;
    float e3 = alS[s3 * H + head] + ald;
    float h0 = bf2f(h[(size_t)s0 * 64 + lane]);
    float h1 = bf2f(h[(size_t)s1 * 64 + lane]);
    float h2 = bf2f(h[(size_t)s2 * 64 + lane]);
    float h3 = bf2f(h[(size_t)s3 * 64 + lane]);
    e0 = e0 > 0.f ? e0 : 0.2f * e0;
    e1 = e1 > 0.f ? e1 : 0.2f * e1;
    e2 = e2 > 0.f ? e2 : 0.2f * e2;
    e3 = e3 > 0.f ? e3 : 0.2f * e3;
    e1 = (rem > 1) ? e1 : -3.0e38f;
    e2 = (rem > 2) ? e2 : -3.0e38f;
    e3 = (rem > 3) ? e3 : -3.0e38f;
    float cm = fmaxf(fmaxf(e0, e1), fmaxf(e2, e3));
    float mn = fmaxf(m, cm);
    float sc = __expf(m - mn);
    float q0 = __expf(e0 - mn), q1 = __expf(e1 - mn);
    float q2 = __expf(e2 - mn), q3 = __expf(e3 - mn);
    ssum = ssum * sc + q0 + q1 + q2 + q3;
    acc  = acc  * sc + q0 * h0 + q1 * h1 + q2 * h2 + q3 * h3;
    m = mn;
  }
  float o = acc / (ssum + 1e-16f) + bias[lane];
  o = o > 0.f ? o : __expf(o) - 1.f;  // ELU
  if constexpr (sizeof(OT) == 2) out[(size_t)wid * 64 + lane] = (OT)f2bf(o);
  else                           out[(size_t)wid * 64 + lane] = o;
}

// ---------------- pooling ----------------
__global__ void cnt_kernel(const int* __restrict__ batch, int* __restrict__ cnts, int n) {
  int i = blockIdx.x * blockDim.x + threadIdx.x;
  if (i < n) atomicAdd(&cnts[batch[i]], 1);
}

__global__ void pool_kernel(const float* __restrict__ h, const int* __restrict__ batch,
                            float* __restrict__ pooled, int n) {
  int wid = (blockIdx.x * blockDim.x + threadIdx.x) >> 6;
  int lane = threadIdx.x & 63;
  int n0 = wid * 64;
  if (n0 >= n) return;
  int n1 = min(n0 + 64, n);
  int g = batch[min(n0 + lane, n - 1)];
  int gf = __shfl(g, 0), gl = __shfl(g, 63);
  if (gf == gl && n1 == n0 + 64) {
    float a = 0.f;
    #pragma unroll 8
    for (int i = n0; i < n1; ++i) a += h[(size_t)i * 64 + lane];
    atomicAdd(&pooled[gf * 64 + lane], a);
  } else {
    int g_cur = batch[n0];
    float a = 0.f;
    for (int i = n0; i < n1; ++i) {
      int gg = batch[i];
      if (gg != g_cur) {
        atomicAdd(&pooled[g_cur * 64 + lane], a);
        a = 0.f; g_cur = gg;
      }
      a += h[(size_t)i * 64 + lane];
    }
    atomicAdd(&pooled[g_cur * 64 + lane], a);
  }
}

// ---------------- classifier + log_softmax ----------------
__global__ __launch_bounds__(128) void cls_kernel(const float* __restrict__ pooled,
    const int* __restrict__ cnts, const float* __restrict__ Wc,
    const float* __restrict__ bc, float* __restrict__ out) {
  int g = threadIdx.x;
  if (g >= NGRAPH) return;
  float inv = 1.f / fmaxf((float)cnts[g], 1.f);
  float p[64];
  #pragma unroll
  for (int k = 0; k < 64; ++k) p[k] = pooled[g * 64 + k] * inv;
  float lg[NCLS];
  float mx = -3.0e38f;
  #pragma unroll
  for (int c = 0; c < NCLS; ++c) {
    float v = bc[c];
    for (int k = 0; k < 64; ++k) v += p[k] * Wc[k * NCLS + c];
    lg[c] = v;
    mx = fmaxf(mx, v);
  }
  float se = 0.f;
  #pragma unroll
  for (int c = 0; c < NCLS; ++c) se += expf(lg[c] - mx);
  float ls = logf(se);
  #pragma unroll
  for (int c = 0; c < NCLS; ++c) out[g * NCLS + c] = lg[c] - mx - ls;
}

extern "C" void kernel_launch(void* const* d_in, const int* in_sizes, int n_in,
                              void* d_out, int out_size, void* d_ws, size_t ws_size,
                              hipStream_t stream) {
  const float* x      = (const float*)d_in[0];
  const int*   ei     = (const int*)d_in[1];
  const int*   batch  = (const int*)d_in[2];
  const float* W1     = (const float*)d_in[3];
  const float* a_src1 = (const float*)d_in[4];
  const float* a_dst1 = (const float*)d_in[5];
  const float* b1     = (const float*)d_in[6];
  const float* W2     = (const float*)d_in[7];
  const float* a_src2 = (const float*)d_in[8];
  const float* a_dst2 = (const float*)d_in[9];
  const float* b2     = (const float*)d_in[10];
  const float* Wc     = (const float*)d_in[11];
  const float* bc     = (const float*)d_in[12];
  float* out = (float*)d_out;

  const int* srcA = ei;
  const int* dstA = ei + N_EDGES;

  char* ws = (char*)d_ws;
  size_t off = 0;
  auto alloc = [&](size_t bytes) -> void* {
    void* p = ws + off;
    off = (off + bytes + 255) & ~(size_t)255;
    return p;
  };
  ushort* h1    = (ushort*)alloc((size_t)N_NODES * 64 * 2);
  ushort* h1b   = (ushort*)alloc((size_t)N_NODES * 64 * 2);
  ushort* h2    = (ushort*)alloc((size_t)N_NODES * 64 * 2);
  float* hout   = (float*)alloc((size_t)N_NODES * 64 * 4);
  float* alS1   = (float*)alloc((size_t)N_NODES * 4 * 4);
  float* alD1   = (float*)alloc((size_t)N_NODES * 4 * 4);
  float* alS2   = (float*)alloc((size_t)N_NODES * 4);
  float* alD2   = (float*)alloc((size_t)N_NODES * 4);
  ushort* w1t   = (ushort*)alloc((size_t)64 * KPAD1 * 2);
  ushort* w2t   = (ushort*)alloc((size_t)64 * 64 * 2);
  int* deg      = (int*)alloc((size_t)N_NODES * 4);
  int* fill     = (int*)alloc((size_t)N_NODES * 4);
  int* indptr   = (int*)alloc((size_t)(N_NODES + 1) * 4);
  int* srcs     = (int*)alloc((size_t)(ETOT + 16) * 4);
  int* bsum     = (int*)alloc(256 * 4);
  int* boff     = (int*)alloc(256 * 4);
  float* pooled = (float*)alloc((size_t)NGRAPH * 64 * 4);
  int* cnts     = (int*)alloc((size_t)NGRAPH * 4);

  hipMemsetAsync(deg, 0, (size_t)N_NODES * 4, stream);
  hipMemsetAsync(fill, 0, (size_t)N_NODES * 4, stream);
  hipMemsetAsync(pooled, 0, (size_t)NGRAPH * 64 * 4, stream);
  hipMemsetAsync(cnts, 0, (size_t)NGRAPH * 4, stream);

  // weights -> bf16 transposed
  cvtT_tile<<<(KPAD1 + 63) / 64, 256, 0, stream>>>(W1, w1t, VOCAB, KPAD1);
  cvtT_tile<<<1, 256, 0, stream>>>(W2, w2t, 64, 64);

  // CSR build (shared by both layers)
  int egrid = (ETOT + 255) / 256;
  hist_kernel<<<egrid, 256, 0, stream>>>(dstA, deg, N_EDGES, ETOT);
  scan_blk<<<SCAN_BLKS, 256, 0, stream>>>(deg, indptr, bsum, N_NODES);
  scan_top<<<1, 256, 0, stream>>>(bsum, boff, indptr, SCAN_BLKS, N_NODES);
  scan_add<<<SCAN_BLKS, 256, 0, stream>>>(indptr, boff, N_NODES);
  scatter_kernel<<<egrid, 256, 0, stream>>>(srcA, dstA, indptr, fill, srcs, N_EDGES, ETOT);

  int nwaveBlocks = (N_NODES * 64 + 255) / 256;
  int gemmBlocks = ((N_NODES + 15) / 16 + 1) / 2;  // 2 waves/block of 128

  // ---- layer 1 ----
  gemm1_kernel<<<gemmBlocks, 128, 0, stream>>>(x, w1t, h1, alS1, alD1, a_src1, a_dst1, N_NODES);
  agg_kernel<4, ushort><<<nwaveBlocks, 256, 0, stream>>>(h1, alS1, alD1, indptr, srcs, b1, h1b, N_NODES);

  // ---- layer 2 ----
  gemm2_kernel<<<gemmBlocks, 128, 0, stream>>>(h1b, w2t, h2, alS2, alD2, a_src2, a_dst2, N_NODES);
  agg_kernel<1, float><<<nwaveBlocks, 256, 0, stream>>>(h2, alS2, alD2, indptr, srcs, b2, hout, N_NODES);

  // ---- pool + classifier ----
  cnt_kernel<<<(N_NODES + 255) / 256, 256, 0, stream>>>(batch, cnts, N_NODES);
  pool_kernel<<<((N_NODES + 63) / 64 * 64 + 255) / 256, 256, 0, stream>>>(hout, batch, pooled, N_NODES);
  cls_kernel<<<1, 128, 0, stream>>>(pooled, cnts, Wc, bc, out);
}